// Round 6
// baseline (28388.943 us; speedup 1.0000x reference)
//
#include <hip/hip_runtime.h>

// LSTM 2-layer fused persistent kernel, full fp32.
// 256 blocks (1 per batch row / CU) x 1024 threads (16 waves -> 4/SIMD,
// 2x the latency hiding of R5's 8-wave config, which measured only
// VALUBusy=46% with both VALU and LDS pipes un-saturated).
// Thread (row, half): row = tid>>1 in [0,512), half = tid&1 splits K.
// Row permutation: g = row&3, j = row>>2, gr = g*128 + j, so unit j's four
// gates are contiguous in gates[4j..4j+4) (float4 c-update).
// VGPR regime: 1024-thr blocks get a 64-VGPR grant (law: 65536/threads,
// proven R1/R2/R3/R5). Live set engineered <= ~60: 8xfloat4 weights (32,
// KEEP4-pinned) + acc4 + bounded LDS temps via partial unroll.
// Whh split per half-row (64 cols): 32 cols in registers, 32 cols from a
// transposed LDS tile Wldst[8][1024] (float4 lane-consecutive reads,
// conflict-free), restaged from L2 per chunk-phase (Whh0 then Whh1).
// Chunk TC=8: A(stage xc + Wldst<-Whh0, carry h0) / B(xp0) / C(L0 serial
// 8 steps) / {stage Wldst<-Whh1 + D(xp1, 2-pass K)} / E(L1 serial 8 steps).

#define NB   256
#define TSEQ 1024
#define II   64
#define HH   128
#define G4   512
#define TC   8
#define NCH  (TSEQ/TC)

#define KEEP4(v) asm volatile("" : "+v"((v).x), "+v"((v).y), "+v"((v).z), "+v"((v).w))

__device__ __forceinline__ float tanh_f(float x){
    float ax = fabsf(x);
    float e  = __expf(2.f*ax);
    float t  = 1.f - 2.f/(e + 1.f);
    return copysignf(t, x);
}

__global__ __launch_bounds__(1024)
void lstm_all(const float* __restrict__ x,
              const float* __restrict__ Wih0, const float* __restrict__ Whh0,
              const float* __restrict__ bih0, const float* __restrict__ bhh0,
              const float* __restrict__ Wih1, const float* __restrict__ Whh1,
              const float* __restrict__ bih1, const float* __restrict__ bhh1,
              const float* __restrict__ Wlin, const float* __restrict__ blin,
              float* __restrict__ out)
{
    const int b    = blockIdx.x;
    const int tid  = threadIdx.x;
    const int row  = tid >> 1;            // gate row 0..511
    const int half = tid & 1;             // K-half
    const int g    = row & 3;             // gate: 0=i 1=f 2=g 3=o
    const int gr   = g * HH + (row >> 2); // row in weight matrices
    const int hb   = half * 64;           // this thread's K-base

    __shared__ __align__(16) float4 Wldst[8][1024];    // 131,072 B
    __shared__ __align__(16) float  xp[TC][G4];        //  16,384 B
    __shared__ __align__(16) float  h0buf[TC+1][HH];   //   4,608 B
    __shared__ __align__(16) float  xc[TC][II];        //   2,048 B
    __shared__ __align__(16) float  gates[G4];         //   2,048 B
    __shared__ __align__(16) float  h1buf[HH];         //     512 B
    // total 156,672 B <= 160 KiB -> 1 block/CU, 16 waves

    float c0 = 0.f, c1 = 0.f;             // cell state (tid<128: unit j=tid)
    const float bias0 = bih0[gr] + bhh0[gr];
    const float bias1 = bih1[gr] + bhh1[gr];
    const bool  is_g  = (g == 2);

    if (tid < HH) { h0buf[0][tid] = 0.f; h1buf[tid] = 0.f; }

    const float* xb = x + (size_t)b * TSEQ * II;

    for (int ch = 0; ch < NCH; ++ch) {
        // ---------- A: stage Wldst<-Whh0 cols [hb+32,hb+64), xc, carry h0 ----------
        {
            const float* wsrc = Whh0 + (size_t)gr * HH + hb + 32;
            #pragma unroll 2
            for (int j = 0; j < 8; ++j)
                Wldst[j][tid] = *(const float4*)(wsrc + 4*j);
        }
        if (tid < 128) {
            ((float4*)&xc[0][0])[tid] =
                ((const float4*)(xb + (size_t)ch * TC * II))[tid];
        }
        if (ch > 0 && tid < HH) h0buf[0][tid] = h0buf[TC][tid];
        __syncthreads();

        // ---------- B: xp0[t][row] = bias0 + Wih0[gr,:].x_t (half K=32) ----------
        {
            float4 w[8];
            const float4* wp = (const float4*)(Wih0 + (size_t)gr * II + half*32);
            #pragma unroll
            for (int i = 0; i < 8; ++i) w[i] = wp[i];
            #pragma unroll
            for (int i = 0; i < 8; ++i) KEEP4(w[i]);
            #pragma unroll 1
            for (int t = 0; t < TC; ++t) {
                float a0=0.f, a1=0.f, a2=0.f, a3=0.f;
                const float4* xv = (const float4*)&xc[t][half*32];
                #pragma unroll 4
                for (int i = 0; i < 8; ++i) {
                    float4 v = xv[i];
                    a0 += w[i].x*v.x; a1 += w[i].y*v.y;
                    a2 += w[i].z*v.z; a3 += w[i].w*v.w;
                }
                float s = (a0+a1)+(a2+a3);
                s += __shfl_xor(s, 1);
                if (half == 0) xp[t][row] = bias0 + s;
            }
        }
        __syncthreads();

        // ---------- C: layer0 serial, 8 steps ----------
        {
            float4 w[8];
            const float4* wp = (const float4*)(Whh0 + (size_t)gr * HH + hb);
            #pragma unroll
            for (int i = 0; i < 8; ++i) w[i] = wp[i];
            #pragma unroll
            for (int i = 0; i < 8; ++i) KEEP4(w[i]);
            #pragma unroll 1
            for (int t = 0; t < TC; ++t) {
                float a0=0.f, a1=0.f, a2=0.f, a3=0.f;
                const float4* hv = (const float4*)&h0buf[t][hb];
                #pragma unroll 4
                for (int i = 0; i < 8; ++i) {
                    float4 v = hv[i];
                    a0 += w[i].x*v.x; a1 += w[i].y*v.y;
                    a2 += w[i].z*v.z; a3 += w[i].w*v.w;
                }
                #pragma unroll 2
                for (int j = 0; j < 8; ++j) {
                    float4 u = Wldst[j][tid];
                    float4 v = hv[8 + j];
                    a0 += u.x*v.x; a1 += u.y*v.y;
                    a2 += u.z*v.z; a3 += u.w*v.w;
                }
                float s = (a0+a1)+(a2+a3);
                s += __shfl_xor(s, 1);
                if (half == 0) {
                    float pre = xp[t][row] + s;
                    float arg = is_g ? pre : 0.5f*pre;
                    float y   = tanh_f(arg);
                    gates[row] = is_g ? y : 0.5f*y + 0.5f;  // sigm via tanh
                }
                __syncthreads();
                if (tid < HH) {
                    float4 q = *(const float4*)&gates[4*tid];  // (i,f,g,o)
                    c0 = q.y*c0 + q.x*q.z;
                    h0buf[t+1][tid] = q.w * tanh_f(c0);
                }
                __syncthreads();
            }
        }

        // ---------- stage Wldst<-Whh1 + D: xp1 (2-pass over half K=64) ----------
        {
            const float* wsrc = Whh1 + (size_t)gr * HH + hb + 32;
            #pragma unroll 2
            for (int j = 0; j < 8; ++j)
                Wldst[j][tid] = *(const float4*)(wsrc + 4*j);
        }
        #pragma unroll 1
        for (int pass = 0; pass < 2; ++pass) {
            float4 w[8];
            const float4* wp = (const float4*)(Wih1 + (size_t)gr * HH + hb + pass*32);
            #pragma unroll
            for (int i = 0; i < 8; ++i) w[i] = wp[i];
            #pragma unroll
            for (int i = 0; i < 8; ++i) KEEP4(w[i]);
            #pragma unroll 1
            for (int t = 0; t < TC; ++t) {
                float a0=0.f, a1=0.f, a2=0.f, a3=0.f;
                const float4* hv = (const float4*)&h0buf[t+1][hb + pass*32];
                #pragma unroll 4
                for (int i = 0; i < 8; ++i) {
                    float4 v = hv[i];
                    a0 += w[i].x*v.x; a1 += w[i].y*v.y;
                    a2 += w[i].z*v.z; a3 += w[i].w*v.w;
                }
                float s = (a0+a1)+(a2+a3);
                s += __shfl_xor(s, 1);
                if (half == 0) {
                    if (pass == 0) xp[t][row] = bias1 + s;
                    else           xp[t][row] += s;
                }
            }
        }
        __syncthreads();

        // ---------- E: layer1 serial, 8 steps ----------
        {
            float4 w[8];
            const float4* wp = (const float4*)(Whh1 + (size_t)gr * HH + hb);
            #pragma unroll
            for (int i = 0; i < 8; ++i) w[i] = wp[i];
            #pragma unroll
            for (int i = 0; i < 8; ++i) KEEP4(w[i]);
            #pragma unroll 1
            for (int t = 0; t < TC; ++t) {
                float a0=0.f, a1=0.f, a2=0.f, a3=0.f;
                const float4* hv = (const float4*)&h1buf[hb];
                #pragma unroll 4
                for (int i = 0; i < 8; ++i) {
                    float4 v = hv[i];
                    a0 += w[i].x*v.x; a1 += w[i].y*v.y;
                    a2 += w[i].z*v.z; a3 += w[i].w*v.w;
                }
                #pragma unroll 2
                for (int j = 0; j < 8; ++j) {
                    float4 u = Wldst[j][tid];
                    float4 v = hv[8 + j];
                    a0 += u.x*v.x; a1 += u.y*v.y;
                    a2 += u.z*v.z; a3 += u.w*v.w;
                }
                float s = (a0+a1)+(a2+a3);
                s += __shfl_xor(s, 1);
                if (half == 0) {
                    float pre = xp[t][row] + s;
                    float arg = is_g ? pre : 0.5f*pre;
                    float y   = tanh_f(arg);
                    gates[row] = is_g ? y : 0.5f*y + 0.5f;
                }
                __syncthreads();
                if (tid < HH) {
                    float4 q = *(const float4*)&gates[4*tid];
                    c1 = q.y*c1 + q.x*q.z;
                    h1buf[tid] = q.w * tanh_f(c1);
                }
                __syncthreads();
            }
        }
    }

    // ---------- final linear: out[b] = h1 . Wlin[0,:] + blin ----------
    if (tid < 64) {
        float s = h1buf[tid]*Wlin[tid] + h1buf[tid+64]*Wlin[tid+64];
        #pragma unroll
        for (int off = 32; off; off >>= 1) s += __shfl_down(s, off);
        if (tid == 0) out[b] = s + blin[0];
    }
}

extern "C" void kernel_launch(void* const* d_in, const int* in_sizes, int n_in,
                              void* d_out, int out_size, void* d_ws, size_t ws_size,
                              hipStream_t stream)
{
    const float* x    = (const float*)d_in[0];
    const float* Wih0 = (const float*)d_in[1];
    const float* Whh0 = (const float*)d_in[2];
    const float* bih0 = (const float*)d_in[3];
    const float* bhh0 = (const float*)d_in[4];
    const float* Wih1 = (const float*)d_in[5];
    const float* Whh1 = (const float*)d_in[6];
    const float* bih1 = (const float*)d_in[7];
    const float* bhh1 = (const float*)d_in[8];
    const float* Wlin = (const float*)d_in[9];
    const float* blin = (const float*)d_in[10];
    float* out = (float*)d_out;

    hipLaunchKernelGGL(lstm_all, dim3(NB), dim3(1024), 0, stream,
                       x, Wih0, Whh0, bih0, bhh0,
                       Wih1, Whh1, bih1, bhh1, Wlin, blin, out);
}

// Round 7
// 6713.893 us; speedup vs baseline: 4.2284x; 4.2284x over previous
//
#include <hip/hip_runtime.h>

// LSTM 2-layer fused persistent kernel — MFMA bf16 hi/lo pair-split, fp32 I/O.
// 256 blocks (1 batch row / CU) x 512 threads, __launch_bounds__(512,2):
// the ONLY proven no-spill regime (128-VGPR grant; 1024-thr = 64 VGPR = spill,
// proven R2/R3/R4/R6 via WRITE_SIZE GBs + SQ_LDS_BANK_CONFLICT==8.053e8).
// Serial recurrence via v_mfma_f32_16x16x32_bf16, N=1 (col 0): each wave owns
// 4 M-tiles (64 gate rows). fp32 emulated as bf16 hi+lo pairs, 3 MFMA terms
// (hi*hi + hi*lo + lo*hi). Weights pre-packed once per launch into d_ws in
// exact A-fragment lane order (pack_w kernel), hi frags in KEEP-pinned VGPRs,
// lo frags ks0 in VGPRs + ks1-3 in LDS (restaged per phase, L2-hot).
// Projections (Wih0.x, Wih1.h0) are MFMA GEMMs with N=16 timestep-columns.
// Fragment maps (m89-verified, guide §3): A[row=lane&15, k=(lane>>4)*8+j],
// B[k=(lane>>4)*8+j, col=lane&15], D[col=lane&15, row=(lane>>4)*4+reg].
// d_ws requirement: 917,504 B (pack regions below).

typedef __attribute__((ext_vector_type(8))) short bf16x8;
typedef __attribute__((ext_vector_type(4))) float f32x4;

#define NB   256
#define TSEQ 1024
#define II   64
#define HH   128
#define G4   512
#define TC   16
#define NCH  (TSEQ/TC)

// d_ws frag regions (16B units). idx = ((w*4+t)*NKS+s)*64 + lane.
#define F_WHH0_HI 0
#define F_WHH0_LO 8192
#define F_WHH1_HI 16384
#define F_WHH1_LO 24576
#define F_WIH1_HI 32768
#define F_WIH1_LO 40960
#define F_WIH0_HI 49152
#define F_WIH0_LO 53248
#define F_TOTAL   57344   // *16B = 917,504 B

#define KEEP4I(v) asm volatile("" : "+v"((v).x), "+v"((v).y), "+v"((v).z), "+v"((v).w))

__device__ __forceinline__ unsigned short f2bf(float f){
    unsigned u = __float_as_uint(f);
    unsigned r = u + 0x7FFFu + ((u >> 16) & 1u);
    return (unsigned short)(r >> 16);
}
__device__ __forceinline__ float bf2f(unsigned short h){
    return __uint_as_float(((unsigned)h) << 16);
}
__device__ __forceinline__ float tanh_f(float x){
    float ax = fabsf(x);
    float e  = __expf(2.f*ax);
    float t  = 1.f - 2.f/(e + 1.f);
    return copysignf(t, x);
}
__device__ __forceinline__ f32x4 mfma_(int4 a, bf16x8 b, f32x4 c){
    return __builtin_amdgcn_mfma_f32_16x16x32_bf16(
        __builtin_bit_cast(bf16x8, a), b, c, 0, 0, 0);
}

// ---------------- pack kernel: fp32 weights -> hi/lo bf16 A-fragments ------
__global__ void pack_w(const float* __restrict__ Wih0, const float* __restrict__ Whh0,
                       const float* __restrict__ Wih1, const float* __restrict__ Whh1,
                       int4* __restrict__ ws)
{
    int fid = blockIdx.x * 256 + threadIdx.x;
    if (fid >= F_TOTAL) return;
    const float* src; int nks; bool lo; int rb;
    if (fid < F_WHH1_HI)      { src = Whh0; nks = 4; lo = fid >= F_WHH0_LO; rb = fid & 8191; }
    else if (fid < F_WIH1_HI) { src = Whh1; nks = 4; lo = fid >= F_WHH1_LO; rb = fid & 8191; }
    else if (fid < F_WIH0_HI) { src = Wih1; nks = 4; lo = fid >= F_WIH1_LO; rb = fid & 8191; }
    else                      { src = Wih0; nks = 2; lo = fid >= F_WIH0_LO; rb = (fid - F_WIH0_HI) & 4095; }
    int lane = rb & 63;
    int rem  = rb >> 6;
    int s    = rem % nks;
    int t    = (rem / nks) & 3;
    int w    = rem / (nks * 4);
    int row  = w * 64 + t * 16 + (lane & 15);
    int K    = nks * 32;
    int k0   = s * 32 + (lane >> 4) * 8;
    const float* p = src + (size_t)row * K + k0;
    unsigned short h[8];
    #pragma unroll
    for (int j = 0; j < 8; ++j){
        float v = p[j];
        unsigned short hi = f2bf(v);
        h[j] = lo ? f2bf(v - bf2f(hi)) : hi;
    }
    int4 o;
    o.x = (int)((unsigned)h[0] | ((unsigned)h[1] << 16));
    o.y = (int)((unsigned)h[2] | ((unsigned)h[3] << 16));
    o.z = (int)((unsigned)h[4] | ((unsigned)h[5] << 16));
    o.w = (int)((unsigned)h[6] | ((unsigned)h[7] << 16));
    ws[fid] = o;
}

// ---------------- serial 16-step recurrence (one layer) --------------------
template<int LAYER>
__device__ __forceinline__ void serial16(
    int w, int lane, int lk, bool col0, int tid,
    const int4* __restrict__ ws,
    int4 (&Wlo)[8][4][3][64],
    float (&xp)[TC][G4],
    unsigned short (&hist_hi)[TC+1][136], unsigned short (&hist_lo)[TC+1][136],
    unsigned short* h1_hi, unsigned short* h1_lo, float* h1f,
    float (&gates)[G4],
    float& c)
{
    const int FHI = LAYER ? F_WHH1_HI : F_WHH0_HI;
    const int FLO = LAYER ? F_WHH1_LO : F_WHH0_LO;
    int4 Ahi[4][4], AloR[4];
    #pragma unroll
    for (int t4 = 0; t4 < 4; ++t4){
        #pragma unroll
        for (int s = 0; s < 4; ++s)
            Ahi[t4][s] = ws[FHI + (((w*4 + t4)*4 + s) << 6) + lane];
        AloR[t4] = ws[FLO + (((w*4 + t4)*4 + 0) << 6) + lane];
    }
    #pragma unroll
    for (int t4 = 0; t4 < 4; ++t4){
        #pragma unroll
        for (int s = 0; s < 4; ++s) KEEP4I(Ahi[t4][s]);
        KEEP4I(AloR[t4]);
    }
    #pragma unroll 1
    for (int t = 0; t < TC; ++t){
        const int4* hh = LAYER ? (const int4*)h1_hi : (const int4*)&hist_hi[t][0];
        const int4* hl = LAYER ? (const int4*)h1_lo : (const int4*)&hist_lo[t][0];
        f32x4 acc[4];
        #pragma unroll
        for (int t4 = 0; t4 < 4; ++t4) acc[t4] = (f32x4){0.f,0.f,0.f,0.f};
        #pragma unroll
        for (int s = 0; s < 4; ++s){
            int4 z = {0,0,0,0};
            int4 vh = hh[4*s + lk];
            int4 vl = hl[4*s + lk];
            bf16x8 bh = __builtin_bit_cast(bf16x8, col0 ? vh : z);
            bf16x8 bl = __builtin_bit_cast(bf16x8, col0 ? vl : z);
            #pragma unroll
            for (int t4 = 0; t4 < 4; ++t4){
                int4 al4 = (s == 0) ? AloR[t4] : Wlo[w][t4][s-1][lane];
                acc[t4] = mfma_(Ahi[t4][s], bh, acc[t4]);
                acc[t4] = mfma_(Ahi[t4][s], bl, acc[t4]);
                acc[t4] = mfma_(al4,        bh, acc[t4]);
            }
            __builtin_amdgcn_sched_barrier(0);  // cap load-hoisting (reg budget)
        }
        #pragma unroll
        for (int t4 = 0; t4 < 4; ++t4){
            int rowb = w*64 + t4*16 + lk*4;
            int gid  = (w*64 + t4*16) >> 7;           // 0=i 1=f 2=g 3=o (wave-uniform)
            f32x4 pre = acc[t4] + *(const f32x4*)&xp[t][rowb];
            float r[4];
            #pragma unroll
            for (int j = 0; j < 4; ++j){
                float p = pre[j];
                float y = tanh_f(gid == 2 ? p : 0.5f*p);
                r[j] = gid == 2 ? y : 0.5f*y + 0.5f;   // sigm via tanh
            }
            if (col0) *(f32x4*)&gates[rowb] = (f32x4){r[0], r[1], r[2], r[3]};
        }
        __syncthreads();
        if (tid < HH){
            float gi = gates[tid],        gf = gates[HH + tid];
            float gg = gates[2*HH + tid], go = gates[3*HH + tid];
            c = gf*c + gi*gg;
            float h = go * tanh_f(c);
            unsigned short hi = f2bf(h);
            unsigned short lo = f2bf(h - bf2f(hi));
            if (LAYER){ h1_hi[tid] = hi; h1_lo[tid] = lo; h1f[tid] = h; }
            else      { hist_hi[t+1][tid] = hi; hist_lo[t+1][tid] = lo; }
        }
        __syncthreads();
    }
}

// ---------------- main persistent kernel -----------------------------------
__global__ __launch_bounds__(512, 2)
void lstm_mfma(const float* __restrict__ x,
               const float* __restrict__ bih0, const float* __restrict__ bhh0,
               const float* __restrict__ bih1, const float* __restrict__ bhh1,
               const float* __restrict__ Wlin, const float* __restrict__ blin,
               const int4* __restrict__ ws,
               float* __restrict__ out)
{
    const int b    = blockIdx.x;
    const int tid  = threadIdx.x;
    const int lane = tid & 63;
    const int w    = tid >> 6;
    const int lm   = lane & 15;
    const int lk   = lane >> 4;
    const bool col0 = (lm == 0);

    __shared__ __align__(16) int4   Wlo[8][4][3][64];           // 98,304 B
    __shared__ __align__(16) float  xp[TC][G4];                 // 32,768 B
    __shared__ __align__(16) unsigned short hist_hi[TC+1][136]; //  4,624 B
    __shared__ __align__(16) unsigned short hist_lo[TC+1][136]; //  4,624 B
    __shared__ __align__(16) unsigned short xc_hi[TC][72];      //  2,304 B
    __shared__ __align__(16) unsigned short xc_lo[TC][72];      //  2,304 B
    __shared__ __align__(16) float  gates[G4];                  //  2,048 B
    __shared__ __align__(16) unsigned short h1_hi[HH];          //    256 B
    __shared__ __align__(16) unsigned short h1_lo[HH];          //    256 B
    __shared__ __align__(16) float  h1f[HH];                    //    512 B
    __shared__ __align__(16) float  bias[2][G4];                //  4,096 B
    // ~152 KB -> 1 block/CU, 8 waves

    bias[0][tid] = bih0[tid] + bhh0[tid];
    bias[1][tid] = bih1[tid] + bhh1[tid];
    if (tid < HH){ hist_hi[0][tid] = 0; hist_lo[0][tid] = 0;
                   h1_hi[tid] = 0; h1_lo[tid] = 0; h1f[tid] = 0.f; }
    float c0 = 0.f, c1 = 0.f;
    const float* xb = x + (size_t)b * TSEQ * II;
    __syncthreads();

    #pragma unroll 1
    for (int ch = 0; ch < NCH; ++ch){
        // ---- A: stage x chunk as bf16 pairs; carry h0 ----
        {
            int i0 = tid, i1 = tid + 512;
            float v0 = xb[(size_t)ch*TC*II + i0];
            float v1 = xb[(size_t)ch*TC*II + i1];
            unsigned short a0 = f2bf(v0), a1 = f2bf(v1);
            xc_hi[i0>>6][i0&63] = a0; xc_lo[i0>>6][i0&63] = f2bf(v0 - bf2f(a0));
            xc_hi[i1>>6][i1&63] = a1; xc_lo[i1>>6][i1&63] = f2bf(v1 - bf2f(a1));
        }
        if (ch > 0 && tid < HH){
            hist_hi[0][tid] = hist_hi[TC][tid];
            hist_lo[0][tid] = hist_lo[TC][tid];
        }
        __syncthreads();

        // ---- B: stage Wlo<-Whh0_lo(ks1-3) + proj xp0 (K=64, B = xc pairs) ----
        {
            #pragma unroll
            for (int t4 = 0; t4 < 4; ++t4)
                #pragma unroll
                for (int s = 1; s < 4; ++s)
                    Wlo[w][t4][s-1][lane] = ws[F_WHH0_LO + (((w*4 + t4)*4 + s) << 6) + lane];

            f32x4 acc[4];
            #pragma unroll
            for (int t4 = 0; t4 < 4; ++t4) acc[t4] = (f32x4){0.f,0.f,0.f,0.f};
            #pragma unroll
            for (int s = 0; s < 2; ++s){
                int4 vh = *(const int4*)&xc_hi[lm][s*32 + lk*8];
                int4 vl = *(const int4*)&xc_lo[lm][s*32 + lk*8];
                bf16x8 bh = __builtin_bit_cast(bf16x8, vh);
                bf16x8 bl = __builtin_bit_cast(bf16x8, vl);
                #pragma unroll
                for (int t4 = 0; t4 < 4; ++t4){
                    int4 ah = ws[F_WIH0_HI + (((w*4 + t4)*2 + s) << 6) + lane];
                    int4 al = ws[F_WIH0_LO + (((w*4 + t4)*2 + s) << 6) + lane];
                    acc[t4] = mfma_(ah, bh, acc[t4]);
                    acc[t4] = mfma_(ah, bl, acc[t4]);
                    acc[t4] = mfma_(al, bh, acc[t4]);
                }
                __builtin_amdgcn_sched_barrier(0);
            }
            #pragma unroll
            for (int t4 = 0; t4 < 4; ++t4){
                int rowb = w*64 + t4*16 + lk*4;
                *(f32x4*)&xp[lm][rowb] = acc[t4] + *(const f32x4*)&bias[0][rowb];
            }
        }
        __syncthreads();

        // ---- C: layer0 serial 16 steps ----
        serial16<0>(w, lane, lk, col0, tid, ws, Wlo, xp, hist_hi, hist_lo,
                    h1_hi, h1_lo, h1f, gates, c0);

        // ---- D: stage Wlo<-Whh1_lo(ks1-3) + proj xp1 (K=128, B = hist pairs) ----
        {
            #pragma unroll
            for (int t4 = 0; t4 < 4; ++t4)
                #pragma unroll
                for (int s = 1; s < 4; ++s)
                    Wlo[w][t4][s-1][lane] = ws[F_WHH1_LO + (((w*4 + t4)*4 + s) << 6) + lane];

            f32x4 acc[4];
            #pragma unroll
            for (int t4 = 0; t4 < 4; ++t4) acc[t4] = (f32x4){0.f,0.f,0.f,0.f};
            #pragma unroll
            for (int s = 0; s < 4; ++s){
                int4 vh = *(const int4*)&hist_hi[lm + 1][s*32 + lk*8];
                int4 vl = *(const int4*)&hist_lo[lm + 1][s*32 + lk*8];
                bf16x8 bh = __builtin_bit_cast(bf16x8, vh);
                bf16x8 bl = __builtin_bit_cast(bf16x8, vl);
                #pragma unroll
                for (int t4 = 0; t4 < 4; ++t4){
                    int4 ah = ws[F_WIH1_HI + (((w*4 + t4)*4 + s) << 6) + lane];
                    int4 al = ws[F_WIH1_LO + (((w*4 + t4)*4 + s) << 6) + lane];
                    acc[t4] = mfma_(ah, bh, acc[t4]);
                    acc[t4] = mfma_(ah, bl, acc[t4]);
                    acc[t4] = mfma_(al, bh, acc[t4]);
                }
                __builtin_amdgcn_sched_barrier(0);
            }
            #pragma unroll
            for (int t4 = 0; t4 < 4; ++t4){
                int rowb = w*64 + t4*16 + lk*4;
                *(f32x4*)&xp[lm][rowb] = acc[t4] + *(const f32x4*)&bias[1][rowb];
            }
        }
        __syncthreads();

        // ---- E: layer1 serial 16 steps ----
        serial16<1>(w, lane, lk, col0, tid, ws, Wlo, xp, hist_hi, hist_lo,
                    h1_hi, h1_lo, h1f, gates, c1);
    }

    // ---- final linear: out[b] = h1 . Wlin[0,:] + blin ----
    if (tid < 64){
        float s = h1f[tid]*Wlin[tid] + h1f[tid+64]*Wlin[tid+64];
        #pragma unroll
        for (int off = 32; off; off >>= 1) s += __shfl_down(s, off);
        if (tid == 0) out[b] = s + blin[0];
    }
}

extern "C" void kernel_launch(void* const* d_in, const int* in_sizes, int n_in,
                              void* d_out, int out_size, void* d_ws, size_t ws_size,
                              hipStream_t stream)
{
    const float* x    = (const float*)d_in[0];
    const float* Wih0 = (const float*)d_in[1];
    const float* Whh0 = (const float*)d_in[2];
    const float* bih0 = (const float*)d_in[3];
    const float* bhh0 = (const float*)d_in[4];
    const float* Wih1 = (const float*)d_in[5];
    const float* Whh1 = (const float*)d_in[6];
    const float* bih1 = (const float*)d_in[7];
    const float* bhh1 = (const float*)d_in[8];
    const float* Wlin = (const float*)d_in[9];
    const float* blin = (const float*)d_in[10];
    int4* ws = (int4*)d_ws;   // requires ws_size >= 917,504 B

    hipLaunchKernelGGL(pack_w, dim3(F_TOTAL/256), dim3(256), 0, stream,
                       Wih0, Whh0, Wih1, Whh1, ws);
    hipLaunchKernelGGL(lstm_mfma, dim3(NB), dim3(512), 0, stream,
                       x, bih0, bhh0, bih1, bhh1, Wlin, blin, ws, (float*)d_out);
}

// Round 8
// 4304.511 us; speedup vs baseline: 6.5952x; 1.5597x over previous
//
#include <hip/hip_runtime.h>

// LSTM 2-layer fused persistent kernel — MFMA bf16 hi/lo pair-split, fp32 I/O.
// 256 blocks (1 batch row / CU) x 512 threads, __launch_bounds__(512,2):
// the ONLY proven no-spill regime (128-VGPR grant; 1024-thr = 64 VGPR = spill).
// Serial recurrence via v_mfma_f32_16x16x32_bf16: each wave owns 4 M-tiles
// (64 gate rows); fp32 emulated as bf16 hi+lo pairs, 3 MFMA terms.
// R8 change vs R7 (which was VALU-bound: 45% VALUBusy, 16 redundant tanh per
// lane): B operand NOT zeroed for cols!=0 -> D column-replicated -> every
// lane valid; activations distributed 1-per-lane via lm-indexed cndmask tree.
// Weights pre-packed once per launch into d_ws (pack_w) in A-fragment lane
// order; hi frags KEEP-pinned in VGPRs, lo frags ks0 in VGPRs + ks1-3 in LDS.
// Fragment maps (m89-verified): A[row=lane&15, k=(lane>>4)*8+j],
// B[k=(lane>>4)*8+j, col=lane&15], D[col=lane&15, row=(lane>>4)*4+reg].
// d_ws requirement: 917,504 B.

typedef __attribute__((ext_vector_type(8))) short bf16x8;
typedef __attribute__((ext_vector_type(4))) float f32x4;

#define NB   256
#define TSEQ 1024
#define II   64
#define HH   128
#define G4   512
#define TC   16
#define NCH  (TSEQ/TC)

// d_ws frag regions (16B units). idx = ((w*4+t)*NKS+s)*64 + lane.
#define F_WHH0_HI 0
#define F_WHH0_LO 8192
#define F_WHH1_HI 16384
#define F_WHH1_LO 24576
#define F_WIH1_HI 32768
#define F_WIH1_LO 40960
#define F_WIH0_HI 49152
#define F_WIH0_LO 53248
#define F_TOTAL   57344   // *16B = 917,504 B

#define KEEP4I(v) asm volatile("" : "+v"((v).x), "+v"((v).y), "+v"((v).z), "+v"((v).w))

__device__ __forceinline__ unsigned short f2bf(float f){
    unsigned u = __float_as_uint(f);
    unsigned r = u + 0x7FFFu + ((u >> 16) & 1u);
    return (unsigned short)(r >> 16);
}
__device__ __forceinline__ float bf2f(unsigned short h){
    return __uint_as_float(((unsigned)h) << 16);
}
__device__ __forceinline__ float tanh_f(float x){
    float ax = fabsf(x);
    float e  = __expf(2.f*ax);
    float t  = 1.f - 2.f/(e + 1.f);
    return copysignf(t, x);
}
__device__ __forceinline__ f32x4 mfma_(int4 a, bf16x8 b, f32x4 c){
    return __builtin_amdgcn_mfma_f32_16x16x32_bf16(
        __builtin_bit_cast(bf16x8, a), b, c, 0, 0, 0);
}

// ---------------- pack kernel: fp32 weights -> hi/lo bf16 A-fragments ------
__global__ void pack_w(const float* __restrict__ Wih0, const float* __restrict__ Whh0,
                       const float* __restrict__ Wih1, const float* __restrict__ Whh1,
                       int4* __restrict__ ws)
{
    int fid = blockIdx.x * 256 + threadIdx.x;
    if (fid >= F_TOTAL) return;
    const float* src; int nks; bool lo; int rb;
    if (fid < F_WHH1_HI)      { src = Whh0; nks = 4; lo = fid >= F_WHH0_LO; rb = fid & 8191; }
    else if (fid < F_WIH1_HI) { src = Whh1; nks = 4; lo = fid >= F_WHH1_LO; rb = fid & 8191; }
    else if (fid < F_WIH0_HI) { src = Wih1; nks = 4; lo = fid >= F_WIH1_LO; rb = fid & 8191; }
    else                      { src = Wih0; nks = 2; lo = fid >= F_WIH0_LO; rb = (fid - F_WIH0_HI) & 4095; }
    int lane = rb & 63;
    int rem  = rb >> 6;
    int s    = rem % nks;
    int t    = (rem / nks) & 3;
    int w    = rem / (nks * 4);
    int row  = w * 64 + t * 16 + (lane & 15);
    int K    = nks * 32;
    int k0   = s * 32 + (lane >> 4) * 8;
    const float* p = src + (size_t)row * K + k0;
    unsigned short h[8];
    #pragma unroll
    for (int j = 0; j < 8; ++j){
        float v = p[j];
        unsigned short hi = f2bf(v);
        h[j] = lo ? f2bf(v - bf2f(hi)) : hi;
    }
    int4 o;
    o.x = (int)((unsigned)h[0] | ((unsigned)h[1] << 16));
    o.y = (int)((unsigned)h[2] | ((unsigned)h[3] << 16));
    o.z = (int)((unsigned)h[4] | ((unsigned)h[5] << 16));
    o.w = (int)((unsigned)h[6] | ((unsigned)h[7] << 16));
    ws[fid] = o;
}

// ---------------- serial 16-step recurrence (one layer) --------------------
template<int LAYER>
__device__ __forceinline__ void serial16(
    int w, int lane, int lk, int lm, int tid,
    const int4* __restrict__ ws,
    int4 (&Wlo)[8][4][3][64],
    float (&xp)[TC][G4],
    unsigned short (&hist_hi)[TC+1][136], unsigned short (&hist_lo)[TC+1][136],
    unsigned short* h1_hi, unsigned short* h1_lo, float* h1f,
    float (&gates)[G4],
    float& c)
{
    const int FHI = LAYER ? F_WHH1_HI : F_WHH0_HI;
    const int FLO = LAYER ? F_WHH1_LO : F_WHH0_LO;
    int4 Ahi[4][4], AloR[4];
    #pragma unroll
    for (int t4 = 0; t4 < 4; ++t4){
        #pragma unroll
        for (int s = 0; s < 4; ++s)
            Ahi[t4][s] = ws[FHI + (((w*4 + t4)*4 + s) << 6) + lane];
        AloR[t4] = ws[FLO + (((w*4 + t4)*4 + 0) << 6) + lane];
    }
    #pragma unroll
    for (int t4 = 0; t4 < 4; ++t4){
        #pragma unroll
        for (int s = 0; s < 4; ++s) KEEP4I(Ahi[t4][s]);
        KEEP4I(AloR[t4]);
    }
    const int arow = w*64 + (lm >> 2)*16 + lk*4 + (lm & 3);  // this lane's row
    const int gid  = w >> 1;                                  // wave-uniform gate
    #pragma unroll 1
    for (int t = 0; t < TC; ++t){
        const int4* hh = LAYER ? (const int4*)h1_hi : (const int4*)&hist_hi[t][0];
        const int4* hl = LAYER ? (const int4*)h1_lo : (const int4*)&hist_lo[t][0];
        f32x4 acc[4];
        #pragma unroll
        for (int t4 = 0; t4 < 4; ++t4) acc[t4] = (f32x4){0.f,0.f,0.f,0.f};
        #pragma unroll
        for (int s = 0; s < 4; ++s){
            // B cols not zeroed: D is column-replicated, every lane valid
            bf16x8 bh = __builtin_bit_cast(bf16x8, hh[4*s + lk]);
            bf16x8 bl = __builtin_bit_cast(bf16x8, hl[4*s + lk]);
            #pragma unroll
            for (int t4 = 0; t4 < 4; ++t4){
                int4 al4 = (s == 0) ? AloR[t4] : Wlo[w][t4][s-1][lane];
                acc[t4] = mfma_(Ahi[t4][s], bh, acc[t4]);
                acc[t4] = mfma_(Ahi[t4][s], bl, acc[t4]);
                acc[t4] = mfma_(al4,        bh, acc[t4]);
            }
            __builtin_amdgcn_sched_barrier(0);  // cap load-hoisting (reg budget)
        }
        // 1 activation per lane: select acc[lm>>2][lm&3] via static cndmask tree
        {
            int sel = lm >> 2;
            f32x4 p01 = (sel & 1) ? acc[1] : acc[0];
            f32x4 p23 = (sel & 1) ? acc[3] : acc[2];
            f32x4 ps  = (sel & 2) ? p23 : p01;
            float v01 = (lm & 1) ? ps[1] : ps[0];
            float v23 = (lm & 1) ? ps[3] : ps[2];
            float v   = (lm & 2) ? v23 : v01;
            float pre = v + xp[t][arow];
            float y   = tanh_f(gid == 2 ? pre : 0.5f*pre);
            gates[arow] = (gid == 2) ? y : 0.5f*y + 0.5f;   // sigm via tanh
        }
        __syncthreads();
        if (tid < HH){
            float gi = gates[tid],        gf = gates[HH + tid];
            float gg = gates[2*HH + tid], go = gates[3*HH + tid];
            c = gf*c + gi*gg;
            float h = go * tanh_f(c);
            unsigned short hi = f2bf(h);
            unsigned short lo = f2bf(h - bf2f(hi));
            if (LAYER){ h1_hi[tid] = hi; h1_lo[tid] = lo; h1f[tid] = h; }
            else      { hist_hi[t+1][tid] = hi; hist_lo[t+1][tid] = lo; }
        }
        __syncthreads();
    }
}

// ---------------- main persistent kernel -----------------------------------
__global__ __launch_bounds__(512, 2)
void lstm_mfma(const float* __restrict__ x,
               const float* __restrict__ bih0, const float* __restrict__ bhh0,
               const float* __restrict__ bih1, const float* __restrict__ bhh1,
               const float* __restrict__ Wlin, const float* __restrict__ blin,
               const int4* __restrict__ ws,
               float* __restrict__ out)
{
    const int b    = blockIdx.x;
    const int tid  = threadIdx.x;
    const int lane = tid & 63;
    const int w    = tid >> 6;
    const int lm   = lane & 15;
    const int lk   = lane >> 4;

    __shared__ __align__(16) int4   Wlo[8][4][3][64];           // 98,304 B
    __shared__ __align__(16) float  xp[TC][G4];                 // 32,768 B
    __shared__ __align__(16) unsigned short hist_hi[TC+1][136]; //  4,624 B
    __shared__ __align__(16) unsigned short hist_lo[TC+1][136]; //  4,624 B
    __shared__ __align__(16) unsigned short xc_hi[TC][72];      //  2,304 B
    __shared__ __align__(16) unsigned short xc_lo[TC][72];      //  2,304 B
    __shared__ __align__(16) float  gates[G4];                  //  2,048 B
    __shared__ __align__(16) unsigned short h1_hi[HH];          //    256 B
    __shared__ __align__(16) unsigned short h1_lo[HH];          //    256 B
    __shared__ __align__(16) float  h1f[HH];                    //    512 B
    __shared__ __align__(16) float  bias[2][G4];                //  4,096 B
    // ~152 KB -> 1 block/CU, 8 waves

    bias[0][tid] = bih0[tid] + bhh0[tid];
    bias[1][tid] = bih1[tid] + bhh1[tid];
    if (tid < HH){ hist_hi[0][tid] = 0; hist_lo[0][tid] = 0;
                   h1_hi[tid] = 0; h1_lo[tid] = 0; h1f[tid] = 0.f; }
    float c0 = 0.f, c1 = 0.f;
    const float* xb = x + (size_t)b * TSEQ * II;
    __syncthreads();

    #pragma unroll 1
    for (int ch = 0; ch < NCH; ++ch){
        // ---- A: stage x chunk as bf16 pairs; carry h0 ----
        {
            int i0 = tid, i1 = tid + 512;
            float v0 = xb[(size_t)ch*TC*II + i0];
            float v1 = xb[(size_t)ch*TC*II + i1];
            unsigned short a0 = f2bf(v0), a1 = f2bf(v1);
            xc_hi[i0>>6][i0&63] = a0; xc_lo[i0>>6][i0&63] = f2bf(v0 - bf2f(a0));
            xc_hi[i1>>6][i1&63] = a1; xc_lo[i1>>6][i1&63] = f2bf(v1 - bf2f(a1));
        }
        if (ch > 0 && tid < HH){
            hist_hi[0][tid] = hist_hi[TC][tid];
            hist_lo[0][tid] = hist_lo[TC][tid];
        }
        __syncthreads();

        // ---- B: stage Wlo<-Whh0_lo(ks1-3) + proj xp0 (K=64, B = xc pairs) ----
        {
            #pragma unroll
            for (int t4 = 0; t4 < 4; ++t4)
                #pragma unroll
                for (int s = 1; s < 4; ++s)
                    Wlo[w][t4][s-1][lane] = ws[F_WHH0_LO + (((w*4 + t4)*4 + s) << 6) + lane];

            f32x4 acc[4];
            #pragma unroll
            for (int t4 = 0; t4 < 4; ++t4) acc[t4] = (f32x4){0.f,0.f,0.f,0.f};
            #pragma unroll
            for (int s = 0; s < 2; ++s){
                int4 vh = *(const int4*)&xc_hi[lm][s*32 + lk*8];
                int4 vl = *(const int4*)&xc_lo[lm][s*32 + lk*8];
                bf16x8 bh = __builtin_bit_cast(bf16x8, vh);
                bf16x8 bl = __builtin_bit_cast(bf16x8, vl);
                #pragma unroll
                for (int t4 = 0; t4 < 4; ++t4){
                    int4 ah = ws[F_WIH0_HI + (((w*4 + t4)*2 + s) << 6) + lane];
                    int4 al = ws[F_WIH0_LO + (((w*4 + t4)*2 + s) << 6) + lane];
                    acc[t4] = mfma_(ah, bh, acc[t4]);
                    acc[t4] = mfma_(ah, bl, acc[t4]);
                    acc[t4] = mfma_(al, bh, acc[t4]);
                }
                __builtin_amdgcn_sched_barrier(0);
            }
            #pragma unroll
            for (int t4 = 0; t4 < 4; ++t4){
                int rowb = w*64 + t4*16 + lk*4;
                *(f32x4*)&xp[lm][rowb] = acc[t4] + *(const f32x4*)&bias[0][rowb];
            }
        }
        __syncthreads();

        // ---- C: layer0 serial 16 steps ----
        serial16<0>(w, lane, lk, lm, tid, ws, Wlo, xp, hist_hi, hist_lo,
                    h1_hi, h1_lo, h1f, gates, c0);

        // ---- D: stage Wlo<-Whh1_lo(ks1-3) + proj xp1 (K=128, B = hist pairs) ----
        {
            #pragma unroll
            for (int t4 = 0; t4 < 4; ++t4)
                #pragma unroll
                for (int s = 1; s < 4; ++s)
                    Wlo[w][t4][s-1][lane] = ws[F_WHH1_LO + (((w*4 + t4)*4 + s) << 6) + lane];

            f32x4 acc[4];
            #pragma unroll
            for (int t4 = 0; t4 < 4; ++t4) acc[t4] = (f32x4){0.f,0.f,0.f,0.f};
            #pragma unroll
            for (int s = 0; s < 4; ++s){
                int4 vh = *(const int4*)&hist_hi[lm + 1][s*32 + lk*8];
                int4 vl = *(const int4*)&hist_lo[lm + 1][s*32 + lk*8];
                bf16x8 bh = __builtin_bit_cast(bf16x8, vh);
                bf16x8 bl = __builtin_bit_cast(bf16x8, vl);
                #pragma unroll
                for (int t4 = 0; t4 < 4; ++t4){
                    int4 ah = ws[F_WIH1_HI + (((w*4 + t4)*4 + s) << 6) + lane];
                    int4 al = ws[F_WIH1_LO + (((w*4 + t4)*4 + s) << 6) + lane];
                    acc[t4] = mfma_(ah, bh, acc[t4]);
                    acc[t4] = mfma_(ah, bl, acc[t4]);
                    acc[t4] = mfma_(al, bh, acc[t4]);
                }
                __builtin_amdgcn_sched_barrier(0);
            }
            #pragma unroll
            for (int t4 = 0; t4 < 4; ++t4){
                int rowb = w*64 + t4*16 + lk*4;
                *(f32x4*)&xp[lm][rowb] = acc[t4] + *(const f32x4*)&bias[1][rowb];
            }
        }
        __syncthreads();

        // ---- E: layer1 serial 16 steps ----
        serial16<1>(w, lane, lk, lm, tid, ws, Wlo, xp, hist_hi, hist_lo,
                    h1_hi, h1_lo, h1f, gates, c1);
    }

    // ---- final linear: out[b] = h1 . Wlin[0,:] + blin ----
    if (tid < 64){
        float s = h1f[tid]*Wlin[tid] + h1f[tid+64]*Wlin[tid+64];
        #pragma unroll
        for (int off = 32; off; off >>= 1) s += __shfl_down(s, off);
        if (tid == 0) out[b] = s + blin[0];
    }
}

extern "C" void kernel_launch(void* const* d_in, const int* in_sizes, int n_in,
                              void* d_out, int out_size, void* d_ws, size_t ws_size,
                              hipStream_t stream)
{
    const float* x    = (const float*)d_in[0];
    const float* Wih0 = (const float*)d_in[1];
    const float* Whh0 = (const float*)d_in[2];
    const float* bih0 = (const float*)d_in[3];
    const float* bhh0 = (const float*)d_in[4];
    const float* Wih1 = (const float*)d_in[5];
    const float* Whh1 = (const float*)d_in[6];
    const float* bih1 = (const float*)d_in[7];
    const float* bhh1 = (const float*)d_in[8];
    const float* Wlin = (const float*)d_in[9];
    const float* blin = (const float*)d_in[10];
    int4* ws = (int4*)d_ws;   // requires ws_size >= 917,504 B

    hipLaunchKernelGGL(pack_w, dim3(F_TOTAL/256), dim3(256), 0, stream,
                       Wih0, Whh0, Wih1, Whh1, ws);
    hipLaunchKernelGGL(lstm_mfma, dim3(NB), dim3(512), 0, stream,
                       x, bih0, bhh0, bih1, bhh1, Wlin, blin, ws, (float*)d_out);
}